// Round 5
// baseline (870.750 us; speedup 1.0000x reference)
//
#include <hip/hip_runtime.h>

// SSIM 3D, round 5. R3 structure (proven exact, 0 conflicts) with:
//  - DSUB=8 -> 2048 blocks = 8 blocks/CU (R3 was grid-capped at 4/CU, 38% occ)
//  - LDS exactly 20480 B (sWc reused for reductions) so 8 blocks fit per CU
//  - __launch_bounds__(256,8) pins VGPR<=64 (R3 used exactly 64) for 8 waves/SIMD
//  - single fused kernel: per-block window factorization (uniform scalar loads)
//    + last-block finalize via ticket (4-byte hipMemsetAsync node zeroes it)
// NO wave_barrier intrinsics (R4 post-mortem: they broke SROA -> scratch spill).

#define NDIM 128
#define TH 4
#define WR (TH + 4)            // 8 W-conv rows
#define DSUB 8
#define NHT (NDIM / TH)        // 32
#define NDT (NDIM / DSUB)      // 16
#define NB 4
#define NBLK (NHT * NDT * NB)  // 2048

__launch_bounds__(256, 8)
__global__ void ssim_main(const float* __restrict__ img1,
                          const float* __restrict__ img2,
                          const float* __restrict__ win,
                          float* __restrict__ partials,
                          unsigned* __restrict__ ticket,
                          float* __restrict__ out) {
    const int bid = blockIdx.x;
    const int th = bid % NHT;
    const int td = (bid / NHT) % NDT;
    const int b  = bid / (NHT * NDT);

    const int h0 = th * TH, d0 = td * DSUB;
    const float* __restrict__ x1 = img1 + (size_t)(b * 2 + 1) * NDIM * NDIM * NDIM;
    const float* __restrict__ x2 = img2 + (size_t)b * NDIM * NDIM * NDIM;

    // window is rank-1: w[i][j][k] = u[i]*v[j]*t[k]; factorize from uniform loads
    float uW[5], vW[5], tW[5];
    {
        const float inv = 1.0f / win[0];
        #pragma unroll
        for (int i = 0; i < 5; ++i) uW[i] = win[i * 25];
        #pragma unroll
        for (int j = 0; j < 5; ++j) vW[j] = win[j * 5] * inv;
        #pragma unroll
        for (int k = 0; k < 5; ++k) tW[k] = win[k] * inv;
    }

    __shared__ float sWc[5][WR][NDIM];   // exactly 20480 B; reused for reductions

    const int tid  = threadIdx.x;
    const int wid  = tid >> 6;
    const int lane = tid & 63;
    // W-conv mapping: 8 rows x 32 col-groups of 4
    const int wrow = tid >> 5;
    const int wcg  = tid & 31;
    const int c0   = wcg * 4;
    const int ghw  = h0 + wrow - 2;
    // H/D mapping: 4 rows x 64 col-pairs of 2
    const int orow = tid >> 6;
    const int oc   = (tid & 63) * 2;

    float2 ring[5][5];                   // [slot][field], static indices only
    float2 accS = make_float2(0.f, 0.f);

#define PHASE(I, P) do {                                                       \
    const int i_ = (I);                                                        \
    const int d_ = d0 - 2 + i_;                                                \
    float4 A0 = make_float4(0,0,0,0), A1 = A0, A2 = A0;                        \
    float4 B0 = A0, B1 = A0, B2 = A0;                                          \
    if (((unsigned)d_ < NDIM) && ((unsigned)ghw < NDIM)) {                     \
        const float* __restrict__ r1_ = x1 + ((size_t)d_ * NDIM + ghw) * NDIM; \
        const float* __restrict__ r2_ = x2 + ((size_t)d_ * NDIM + ghw) * NDIM; \
        if (wcg > 0)  { A0 = *(const float4*)(r1_ + c0 - 4);                   \
                        B0 = *(const float4*)(r2_ + c0 - 4); }                 \
        A1 = *(const float4*)(r1_ + c0);                                       \
        B1 = *(const float4*)(r2_ + c0);                                       \
        if (wcg < 31) { A2 = *(const float4*)(r1_ + c0 + 4);                   \
                        B2 = *(const float4*)(r2_ + c0 + 4); }                 \
    }                                                                          \
    float ra[12] = {A0.x,A0.y,A0.z,A0.w, A1.x,A1.y,A1.z,A1.w,                  \
                    A2.x,A2.y,A2.z,A2.w};                                      \
    float rb[12] = {B0.x,B0.y,B0.z,B0.w, B1.x,B1.y,B1.z,B1.w,                  \
                    B2.x,B2.y,B2.z,B2.w};                                      \
    float m1v[4], m2v[4], q11v[4], q22v[4], q12v[4];                           \
    _Pragma("unroll")                                                          \
    for (int k_ = 0; k_ < 4; ++k_) {                                           \
        float m1_=0.f, m2_=0.f, q11_=0.f, q22_=0.f, q12_=0.f;                  \
        _Pragma("unroll")                                                      \
        for (int c_ = 0; c_ < 5; ++c_) {                                       \
            const float a_ = ra[k_ + c_ + 2], b_ = rb[k_ + c_ + 2];            \
            const float ta_ = tW[c_] * a_, tb_ = tW[c_] * b_;                  \
            m1_ += ta_; m2_ += tb_;                                            \
            q11_ += ta_ * a_; q22_ += tb_ * b_; q12_ += ta_ * b_;              \
        }                                                                      \
        m1v[k_]=m1_; m2v[k_]=m2_; q11v[k_]=q11_; q22v[k_]=q22_; q12v[k_]=q12_; \
    }                                                                          \
    __syncthreads();   /* prev phase's reads of sWc complete */                \
    *(float4*)&sWc[0][wrow][c0] = make_float4(m1v[0],m1v[1],m1v[2],m1v[3]);    \
    *(float4*)&sWc[1][wrow][c0] = make_float4(m2v[0],m2v[1],m2v[2],m2v[3]);    \
    *(float4*)&sWc[2][wrow][c0] = make_float4(q11v[0],q11v[1],q11v[2],q11v[3]);\
    *(float4*)&sWc[3][wrow][c0] = make_float4(q22v[0],q22v[1],q22v[2],q22v[3]);\
    *(float4*)&sWc[4][wrow][c0] = make_float4(q12v[0],q12v[1],q12v[2],q12v[3]);\
    __syncthreads();   /* writes visible */                                    \
    _Pragma("unroll")                                                          \
    for (int f_ = 0; f_ < 5; ++f_) {                                           \
        float2 F_ = make_float2(0.f, 0.f);                                     \
        _Pragma("unroll")                                                      \
        for (int r_ = 0; r_ < 5; ++r_) {                                       \
            const float2 wv_ = *(const float2*)&sWc[f_][orow + r_][oc];        \
            F_.x += vW[r_] * wv_.x;                                            \
            F_.y += vW[r_] * wv_.y;                                            \
        }                                                                      \
        ring[(P)][f_] = F_;                                                    \
    }                                                                          \
    if (i_ >= 4) {                                                             \
        float2 F0 = make_float2(0,0), F1 = F0, F2 = F0, F3 = F0, F4 = F0;      \
        _Pragma("unroll")                                                      \
        for (int j_ = 0; j_ < 5; ++j_) {                                       \
            const int s_ = ((P) + 1 + j_) % 5;                                 \
            const float uw_ = uW[j_];                                          \
            F0.x += uw_*ring[s_][0].x; F0.y += uw_*ring[s_][0].y;              \
            F1.x += uw_*ring[s_][1].x; F1.y += uw_*ring[s_][1].y;              \
            F2.x += uw_*ring[s_][2].x; F2.y += uw_*ring[s_][2].y;              \
            F3.x += uw_*ring[s_][3].x; F3.y += uw_*ring[s_][3].y;              \
            F4.x += uw_*ring[s_][4].x; F4.y += uw_*ring[s_][4].y;              \
        }                                                                      \
        {                                                                      \
            const float mu1 = F0.x, mu2 = F1.x;                                \
            const float m11 = mu1*mu1, m22 = mu2*mu2, m12 = mu1*mu2;           \
            const float num = (2.f*m12 + 1e-4f) * (2.f*(F4.x - m12) + 9e-4f);  \
            const float den = (m11 + m22 + 1e-4f) *                            \
                              ((F2.x - m11) + (F3.x - m22) + 9e-4f);           \
            accS.x += __fdividef(num, den);                                    \
        }                                                                      \
        {                                                                      \
            const float mu1 = F0.y, mu2 = F1.y;                                \
            const float m11 = mu1*mu1, m22 = mu2*mu2, m12 = mu1*mu2;           \
            const float num = (2.f*m12 + 1e-4f) * (2.f*(F4.y - m12) + 9e-4f);  \
            const float den = (m11 + m22 + 1e-4f) *                            \
                              ((F2.y - m11) + (F3.y - m22) + 9e-4f);           \
            accS.y += __fdividef(num, den);                                    \
        }                                                                      \
    }                                                                          \
} while (0)

    // 12 phases: d0-2 .. d0+9; ring slot = i % 5; outputs at i>=4 (dd=d0..d0+7)
    PHASE(0, 0);  PHASE(1, 1);  PHASE(2, 2);  PHASE(3, 3);  PHASE(4, 4);
    PHASE(5, 0);  PHASE(6, 1);  PHASE(7, 2);  PHASE(8, 3);  PHASE(9, 4);
    PHASE(10, 0); PHASE(11, 1);
#undef PHASE

    // ---- block reduction (reuse sWc as scratch) ----
    float acc = accS.x + accS.y;
    #pragma unroll
    for (int off = 32; off > 0; off >>= 1)
        acc += __shfl_down(acc, off, 64);
    __syncthreads();                    // all phase reads of sWc done
    float* sF = (float*)sWc;
    if (lane == 0) sF[wid] = acc;
    __syncthreads();
    unsigned* sFlag = ((unsigned*)sWc) + 4;
    if (tid == 0) {
        const float blockSum = sF[0] + sF[1] + sF[2] + sF[3];
        partials[bid] = blockSum;
        __threadfence();                            // release partials
        const unsigned t = atomicAdd(ticket, 1u);   // device-scope
        *sFlag = (t == (unsigned)(NBLK - 1)) ? 1u : 0u;
    }
    __syncthreads();
    if (*sFlag) {
        __threadfence();                // acquire: invalidate stale cache lines
        double s = 0.0;
        for (int i = tid; i < NBLK; i += 256) s += (double)partials[i];
        #pragma unroll
        for (int off = 32; off > 0; off >>= 1)
            s += __shfl_down(s, off, 64);
        __syncthreads();
        double* sD = (double*)sWc;
        if (lane == 0) sD[wid] = s;
        __syncthreads();
        if (tid == 0)
            out[0] = 1.0f - (float)((sD[0] + sD[1] + sD[2] + sD[3]) /
                                    (double)(4LL * 128 * 128 * 128));
    }
}

extern "C" void kernel_launch(void* const* d_in, const int* in_sizes, int n_in,
                              void* d_out, int out_size, void* d_ws, size_t ws_size,
                              hipStream_t stream) {
    const float* img1 = (const float*)d_in[0];   // (4,2,128,128,128) fp32
    const float* img2 = (const float*)d_in[1];   // (4,1,128,128,128) fp32
    const float* win  = (const float*)d_in[2];   // (1,1,5,5,5) fp32
    float* out = (float*)d_out;
    float* ws  = (float*)d_ws;
    float*    partials = ws;                         // NBLK floats, all rewritten
    unsigned* ticket   = (unsigned*)(ws + NBLK);     // zeroed below each launch

    hipMemsetAsync(ticket, 0, sizeof(unsigned), stream);
    hipLaunchKernelGGL(ssim_main, dim3(NBLK), dim3(256), 0, stream,
                       img1, img2, win, partials, ticket, out);
}

// Round 6
// 778.678 us; speedup vs baseline: 1.1182x; 1.1182x over previous
//
#include <hip/hip_runtime.h>

// SSIM 3D, round 6. Identical to R5 except __launch_bounds__(256,4):
// R5's (256,8) capped VGPR at 32 -> scratch spill (2.3 GB HBM traffic, 791us).
// (256,4) reproduces R3's proven VGPR=64 codegen; at 64 VGPR the HW can still
// run 8 waves/SIMD, and LDS is exactly 20480 B -> 8 blocks/CU, grid 2048 = 8/CU.
//  - DSUB=8 -> 2048 blocks (R3 was grid-capped at 4 blocks/CU)
//  - sWc reused for reductions (no extra LDS)
//  - single fused kernel: per-block rank-1 window factorization (uniform
//    scalar loads) + last-block finalize via ticket (hipMemsetAsync zeroes it)
// NO wave_barrier intrinsics (R4: they broke SROA -> scratch spill).

#define NDIM 128
#define TH 4
#define WR (TH + 4)            // 8 W-conv rows
#define DSUB 8
#define NHT (NDIM / TH)        // 32
#define NDT (NDIM / DSUB)      // 16
#define NB 4
#define NBLK (NHT * NDT * NB)  // 2048

__launch_bounds__(256, 4)
__global__ void ssim_main(const float* __restrict__ img1,
                          const float* __restrict__ img2,
                          const float* __restrict__ win,
                          float* __restrict__ partials,
                          unsigned* __restrict__ ticket,
                          float* __restrict__ out) {
    const int bid = blockIdx.x;
    const int th = bid % NHT;
    const int td = (bid / NHT) % NDT;
    const int b  = bid / (NHT * NDT);

    const int h0 = th * TH, d0 = td * DSUB;
    const float* __restrict__ x1 = img1 + (size_t)(b * 2 + 1) * NDIM * NDIM * NDIM;
    const float* __restrict__ x2 = img2 + (size_t)b * NDIM * NDIM * NDIM;

    // window is rank-1: w[i][j][k] = u[i]*v[j]*t[k]; factorize from uniform loads
    float uW[5], vW[5], tW[5];
    {
        const float inv = 1.0f / win[0];
        #pragma unroll
        for (int i = 0; i < 5; ++i) uW[i] = win[i * 25];
        #pragma unroll
        for (int j = 0; j < 5; ++j) vW[j] = win[j * 5] * inv;
        #pragma unroll
        for (int k = 0; k < 5; ++k) tW[k] = win[k] * inv;
    }

    __shared__ float sWc[5][WR][NDIM];   // exactly 20480 B; reused for reductions

    const int tid  = threadIdx.x;
    const int wid  = tid >> 6;
    const int lane = tid & 63;
    // W-conv mapping: 8 rows x 32 col-groups of 4
    const int wrow = tid >> 5;
    const int wcg  = tid & 31;
    const int c0   = wcg * 4;
    const int ghw  = h0 + wrow - 2;
    // H/D mapping: 4 rows x 64 col-pairs of 2
    const int orow = tid >> 6;
    const int oc   = (tid & 63) * 2;

    float2 ring[5][5];                   // [slot][field], static indices only
    float2 accS = make_float2(0.f, 0.f);

#define PHASE(I, P) do {                                                       \
    const int i_ = (I);                                                        \
    const int d_ = d0 - 2 + i_;                                                \
    float4 A0 = make_float4(0,0,0,0), A1 = A0, A2 = A0;                        \
    float4 B0 = A0, B1 = A0, B2 = A0;                                          \
    if (((unsigned)d_ < NDIM) && ((unsigned)ghw < NDIM)) {                     \
        const float* __restrict__ r1_ = x1 + ((size_t)d_ * NDIM + ghw) * NDIM; \
        const float* __restrict__ r2_ = x2 + ((size_t)d_ * NDIM + ghw) * NDIM; \
        if (wcg > 0)  { A0 = *(const float4*)(r1_ + c0 - 4);                   \
                        B0 = *(const float4*)(r2_ + c0 - 4); }                 \
        A1 = *(const float4*)(r1_ + c0);                                       \
        B1 = *(const float4*)(r2_ + c0);                                       \
        if (wcg < 31) { A2 = *(const float4*)(r1_ + c0 + 4);                   \
                        B2 = *(const float4*)(r2_ + c0 + 4); }                 \
    }                                                                          \
    float ra[12] = {A0.x,A0.y,A0.z,A0.w, A1.x,A1.y,A1.z,A1.w,                  \
                    A2.x,A2.y,A2.z,A2.w};                                      \
    float rb[12] = {B0.x,B0.y,B0.z,B0.w, B1.x,B1.y,B1.z,B1.w,                  \
                    B2.x,B2.y,B2.z,B2.w};                                      \
    float m1v[4], m2v[4], q11v[4], q22v[4], q12v[4];                           \
    _Pragma("unroll")                                                          \
    for (int k_ = 0; k_ < 4; ++k_) {                                           \
        float m1_=0.f, m2_=0.f, q11_=0.f, q22_=0.f, q12_=0.f;                  \
        _Pragma("unroll")                                                      \
        for (int c_ = 0; c_ < 5; ++c_) {                                       \
            const float a_ = ra[k_ + c_ + 2], b_ = rb[k_ + c_ + 2];            \
            const float ta_ = tW[c_] * a_, tb_ = tW[c_] * b_;                  \
            m1_ += ta_; m2_ += tb_;                                            \
            q11_ += ta_ * a_; q22_ += tb_ * b_; q12_ += ta_ * b_;              \
        }                                                                      \
        m1v[k_]=m1_; m2v[k_]=m2_; q11v[k_]=q11_; q22v[k_]=q22_; q12v[k_]=q12_; \
    }                                                                          \
    __syncthreads();   /* prev phase's reads of sWc complete */                \
    *(float4*)&sWc[0][wrow][c0] = make_float4(m1v[0],m1v[1],m1v[2],m1v[3]);    \
    *(float4*)&sWc[1][wrow][c0] = make_float4(m2v[0],m2v[1],m2v[2],m2v[3]);    \
    *(float4*)&sWc[2][wrow][c0] = make_float4(q11v[0],q11v[1],q11v[2],q11v[3]);\
    *(float4*)&sWc[3][wrow][c0] = make_float4(q22v[0],q22v[1],q22v[2],q22v[3]);\
    *(float4*)&sWc[4][wrow][c0] = make_float4(q12v[0],q12v[1],q12v[2],q12v[3]);\
    __syncthreads();   /* writes visible */                                    \
    _Pragma("unroll")                                                          \
    for (int f_ = 0; f_ < 5; ++f_) {                                           \
        float2 F_ = make_float2(0.f, 0.f);                                     \
        _Pragma("unroll")                                                      \
        for (int r_ = 0; r_ < 5; ++r_) {                                       \
            const float2 wv_ = *(const float2*)&sWc[f_][orow + r_][oc];        \
            F_.x += vW[r_] * wv_.x;                                            \
            F_.y += vW[r_] * wv_.y;                                            \
        }                                                                      \
        ring[(P)][f_] = F_;                                                    \
    }                                                                          \
    if (i_ >= 4) {                                                             \
        float2 F0 = make_float2(0,0), F1 = F0, F2 = F0, F3 = F0, F4 = F0;      \
        _Pragma("unroll")                                                      \
        for (int j_ = 0; j_ < 5; ++j_) {                                       \
            const int s_ = ((P) + 1 + j_) % 5;                                 \
            const float uw_ = uW[j_];                                          \
            F0.x += uw_*ring[s_][0].x; F0.y += uw_*ring[s_][0].y;              \
            F1.x += uw_*ring[s_][1].x; F1.y += uw_*ring[s_][1].y;              \
            F2.x += uw_*ring[s_][2].x; F2.y += uw_*ring[s_][2].y;              \
            F3.x += uw_*ring[s_][3].x; F3.y += uw_*ring[s_][3].y;              \
            F4.x += uw_*ring[s_][4].x; F4.y += uw_*ring[s_][4].y;              \
        }                                                                      \
        {                                                                      \
            const float mu1 = F0.x, mu2 = F1.x;                                \
            const float m11 = mu1*mu1, m22 = mu2*mu2, m12 = mu1*mu2;           \
            const float num = (2.f*m12 + 1e-4f) * (2.f*(F4.x - m12) + 9e-4f);  \
            const float den = (m11 + m22 + 1e-4f) *                            \
                              ((F2.x - m11) + (F3.x - m22) + 9e-4f);           \
            accS.x += __fdividef(num, den);                                    \
        }                                                                      \
        {                                                                      \
            const float mu1 = F0.y, mu2 = F1.y;                                \
            const float m11 = mu1*mu1, m22 = mu2*mu2, m12 = mu1*mu2;           \
            const float num = (2.f*m12 + 1e-4f) * (2.f*(F4.y - m12) + 9e-4f);  \
            const float den = (m11 + m22 + 1e-4f) *                            \
                              ((F2.y - m11) + (F3.y - m22) + 9e-4f);           \
            accS.y += __fdividef(num, den);                                    \
        }                                                                      \
    }                                                                          \
} while (0)

    // 12 phases: d0-2 .. d0+9; ring slot = i % 5; outputs at i>=4 (dd=d0..d0+7)
    PHASE(0, 0);  PHASE(1, 1);  PHASE(2, 2);  PHASE(3, 3);  PHASE(4, 4);
    PHASE(5, 0);  PHASE(6, 1);  PHASE(7, 2);  PHASE(8, 3);  PHASE(9, 4);
    PHASE(10, 0); PHASE(11, 1);
#undef PHASE

    // ---- block reduction (reuse sWc as scratch) ----
    float acc = accS.x + accS.y;
    #pragma unroll
    for (int off = 32; off > 0; off >>= 1)
        acc += __shfl_down(acc, off, 64);
    __syncthreads();                    // all phase reads of sWc done
    float* sF = (float*)sWc;
    if (lane == 0) sF[wid] = acc;
    __syncthreads();
    unsigned* sFlag = ((unsigned*)sWc) + 4;
    if (tid == 0) {
        const float blockSum = sF[0] + sF[1] + sF[2] + sF[3];
        partials[bid] = blockSum;
        __threadfence();                            // release partials
        const unsigned t = atomicAdd(ticket, 1u);   // device-scope
        *sFlag = (t == (unsigned)(NBLK - 1)) ? 1u : 0u;
    }
    __syncthreads();
    if (*sFlag) {
        __threadfence();                // acquire: invalidate stale cache lines
        double s = 0.0;
        for (int i = tid; i < NBLK; i += 256) s += (double)partials[i];
        #pragma unroll
        for (int off = 32; off > 0; off >>= 1)
            s += __shfl_down(s, off, 64);
        __syncthreads();
        double* sD = (double*)sWc;
        if (lane == 0) sD[wid] = s;
        __syncthreads();
        if (tid == 0)
            out[0] = 1.0f - (float)((sD[0] + sD[1] + sD[2] + sD[3]) /
                                    (double)(4LL * 128 * 128 * 128));
    }
}

extern "C" void kernel_launch(void* const* d_in, const int* in_sizes, int n_in,
                              void* d_out, int out_size, void* d_ws, size_t ws_size,
                              hipStream_t stream) {
    const float* img1 = (const float*)d_in[0];   // (4,2,128,128,128) fp32
    const float* img2 = (const float*)d_in[1];   // (4,1,128,128,128) fp32
    const float* win  = (const float*)d_in[2];   // (1,1,5,5,5) fp32
    float* out = (float*)d_out;
    float* ws  = (float*)d_ws;
    float*    partials = ws;                         // NBLK floats, all rewritten
    unsigned* ticket   = (unsigned*)(ws + NBLK);     // zeroed below each launch

    hipMemsetAsync(ticket, 0, sizeof(unsigned), stream);
    hipLaunchKernelGGL(ssim_main, dim3(NBLK), dim3(256), 0, stream,
                       img1, img2, win, partials, ticket, out);
}

// Round 7
// 627.165 us; speedup vs baseline: 1.3884x; 1.2416x over previous
//
#include <hip/hip_runtime.h>

// SSIM 3D, round 7. EXACTLY R3's proven 3-kernel structure (VGPR 64, no
// spill, absmax 0) with only DSUB 16->8 (grid 1024->2048). R3 was capped at
// 4 blocks/CU by grid size; 2048 blocks -> 7 resident/CU (LDS 20992 B).
// Deliberately NOT trimming LDS to 20480: R6 showed an 8-blocks/CU LDS
// footprint makes the backend clamp the VGPR budget to 64 and spill the
// phase arrays (1.1 GB scratch traffic). Separate sRed kept for same reason.
// No fused finalize tail (R6 spill suspect), no wave_barrier (R4 spill).

#define NDIM 128
#define TH 4
#define WR (TH + 4)            // 8 W-conv rows
#define DSUB 8
#define NHT (NDIM / TH)        // 32
#define NDT (NDIM / DSUB)      // 16
#define NB 4
#define NBLK (NHT * NDT * NB)  // 2048

__global__ void factorize_window(const float* __restrict__ w, float* __restrict__ ws) {
    if (threadIdx.x == 0) {
        float w000 = w[0];
        #pragma unroll
        for (int i = 0; i < 5; ++i) ws[i]      = w[i * 25];
        #pragma unroll
        for (int j = 0; j < 5; ++j) ws[5 + j]  = w[j * 5] / w000;
        #pragma unroll
        for (int k = 0; k < 5; ++k) ws[10 + k] = w[k] / w000;
    }
}

__launch_bounds__(256, 4)
__global__ void ssim_main(const float* __restrict__ img1,
                          const float* __restrict__ img2,
                          const float* __restrict__ wfac,
                          float* __restrict__ partials) {
    const int bid = blockIdx.x;
    const int th = bid % NHT;
    const int td = (bid / NHT) % NDT;
    const int b  = bid / (NHT * NDT);

    const int h0 = th * TH, d0 = td * DSUB;
    const float* __restrict__ x1 = img1 + (size_t)(b * 2 + 1) * NDIM * NDIM * NDIM;
    const float* __restrict__ x2 = img2 + (size_t)b * NDIM * NDIM * NDIM;

    float uW[5], vW[5], tW[5];
    #pragma unroll
    for (int i = 0; i < 5; ++i) { uW[i] = wfac[i]; vW[i] = wfac[5 + i]; tW[i] = wfac[10 + i]; }

    __shared__ float sWc[5][WR][NDIM];   // 20480 B
    __shared__ float sRed[4];            // separate: keeps LDS block at 20992 -> 7 blk/CU

    const int tid  = threadIdx.x;
    // W-conv mapping: 8 rows x 32 col-groups of 4
    const int wrow = tid >> 5;
    const int wcg  = tid & 31;
    const int c0   = wcg * 4;
    const int ghw  = h0 + wrow - 2;
    // H/D mapping: 4 rows x 64 col-pairs of 2
    const int orow = tid >> 6;
    const int oc   = (tid & 63) * 2;

    float2 ring[5][5];                   // [slot][field], static indices only
    float2 accS = make_float2(0.f, 0.f);

#define PHASE(I, P) do {                                                       \
    const int i_ = (I);                                                        \
    const int d_ = d0 - 2 + i_;                                                \
    float4 A0 = make_float4(0,0,0,0), A1 = A0, A2 = A0;                        \
    float4 B0 = A0, B1 = A0, B2 = A0;                                          \
    if (((unsigned)d_ < NDIM) && ((unsigned)ghw < NDIM)) {                     \
        const float* __restrict__ r1_ = x1 + ((size_t)d_ * NDIM + ghw) * NDIM; \
        const float* __restrict__ r2_ = x2 + ((size_t)d_ * NDIM + ghw) * NDIM; \
        if (wcg > 0)  { A0 = *(const float4*)(r1_ + c0 - 4);                   \
                        B0 = *(const float4*)(r2_ + c0 - 4); }                 \
        A1 = *(const float4*)(r1_ + c0);                                       \
        B1 = *(const float4*)(r2_ + c0);                                       \
        if (wcg < 31) { A2 = *(const float4*)(r1_ + c0 + 4);                   \
                        B2 = *(const float4*)(r2_ + c0 + 4); }                 \
    }                                                                          \
    float ra[12] = {A0.x,A0.y,A0.z,A0.w, A1.x,A1.y,A1.z,A1.w,                  \
                    A2.x,A2.y,A2.z,A2.w};                                      \
    float rb[12] = {B0.x,B0.y,B0.z,B0.w, B1.x,B1.y,B1.z,B1.w,                  \
                    B2.x,B2.y,B2.z,B2.w};                                      \
    float m1v[4], m2v[4], q11v[4], q22v[4], q12v[4];                           \
    _Pragma("unroll")                                                          \
    for (int k_ = 0; k_ < 4; ++k_) {                                           \
        float m1_=0.f, m2_=0.f, q11_=0.f, q22_=0.f, q12_=0.f;                  \
        _Pragma("unroll")                                                      \
        for (int c_ = 0; c_ < 5; ++c_) {                                       \
            const float a_ = ra[k_ + c_ + 2], b_ = rb[k_ + c_ + 2];            \
            const float ta_ = tW[c_] * a_, tb_ = tW[c_] * b_;                  \
            m1_ += ta_; m2_ += tb_;                                            \
            q11_ += ta_ * a_; q22_ += tb_ * b_; q12_ += ta_ * b_;              \
        }                                                                      \
        m1v[k_]=m1_; m2v[k_]=m2_; q11v[k_]=q11_; q22v[k_]=q22_; q12v[k_]=q12_; \
    }                                                                          \
    __syncthreads();   /* prev phase's reads of sWc complete */                \
    *(float4*)&sWc[0][wrow][c0] = make_float4(m1v[0],m1v[1],m1v[2],m1v[3]);    \
    *(float4*)&sWc[1][wrow][c0] = make_float4(m2v[0],m2v[1],m2v[2],m2v[3]);    \
    *(float4*)&sWc[2][wrow][c0] = make_float4(q11v[0],q11v[1],q11v[2],q11v[3]);\
    *(float4*)&sWc[3][wrow][c0] = make_float4(q22v[0],q22v[1],q22v[2],q22v[3]);\
    *(float4*)&sWc[4][wrow][c0] = make_float4(q12v[0],q12v[1],q12v[2],q12v[3]);\
    __syncthreads();   /* writes visible */                                    \
    _Pragma("unroll")                                                          \
    for (int f_ = 0; f_ < 5; ++f_) {                                           \
        float2 F_ = make_float2(0.f, 0.f);                                     \
        _Pragma("unroll")                                                      \
        for (int r_ = 0; r_ < 5; ++r_) {                                       \
            const float2 wv_ = *(const float2*)&sWc[f_][orow + r_][oc];        \
            F_.x += vW[r_] * wv_.x;                                            \
            F_.y += vW[r_] * wv_.y;                                            \
        }                                                                      \
        ring[(P)][f_] = F_;                                                    \
    }                                                                          \
    if (i_ >= 4) {                                                             \
        float2 F0 = make_float2(0,0), F1 = F0, F2 = F0, F3 = F0, F4 = F0;      \
        _Pragma("unroll")                                                      \
        for (int j_ = 0; j_ < 5; ++j_) {                                       \
            const int s_ = ((P) + 1 + j_) % 5;                                 \
            const float uw_ = uW[j_];                                          \
            F0.x += uw_*ring[s_][0].x; F0.y += uw_*ring[s_][0].y;              \
            F1.x += uw_*ring[s_][1].x; F1.y += uw_*ring[s_][1].y;              \
            F2.x += uw_*ring[s_][2].x; F2.y += uw_*ring[s_][2].y;              \
            F3.x += uw_*ring[s_][3].x; F3.y += uw_*ring[s_][3].y;              \
            F4.x += uw_*ring[s_][4].x; F4.y += uw_*ring[s_][4].y;              \
        }                                                                      \
        {                                                                      \
            const float mu1 = F0.x, mu2 = F1.x;                                \
            const float m11 = mu1*mu1, m22 = mu2*mu2, m12 = mu1*mu2;           \
            const float num = (2.f*m12 + 1e-4f) * (2.f*(F4.x - m12) + 9e-4f);  \
            const float den = (m11 + m22 + 1e-4f) *                            \
                              ((F2.x - m11) + (F3.x - m22) + 9e-4f);           \
            accS.x += __fdividef(num, den);                                    \
        }                                                                      \
        {                                                                      \
            const float mu1 = F0.y, mu2 = F1.y;                                \
            const float m11 = mu1*mu1, m22 = mu2*mu2, m12 = mu1*mu2;           \
            const float num = (2.f*m12 + 1e-4f) * (2.f*(F4.y - m12) + 9e-4f);  \
            const float den = (m11 + m22 + 1e-4f) *                            \
                              ((F2.y - m11) + (F3.y - m22) + 9e-4f);           \
            accS.y += __fdividef(num, den);                                    \
        }                                                                      \
    }                                                                          \
} while (0)

    // 12 phases: d0-2 .. d0+9; ring slot = i % 5; outputs at i>=4 (dd=d0..d0+7)
    PHASE(0, 0);  PHASE(1, 1);  PHASE(2, 2);  PHASE(3, 3);  PHASE(4, 4);
    PHASE(5, 0);  PHASE(6, 1);  PHASE(7, 2);  PHASE(8, 3);  PHASE(9, 4);
    PHASE(10, 0); PHASE(11, 1);
#undef PHASE

    float acc = accS.x + accS.y;
    #pragma unroll
    for (int off = 32; off > 0; off >>= 1)
        acc += __shfl_down(acc, off, 64);
    __syncthreads();
    if ((tid & 63) == 0) sRed[tid >> 6] = acc;
    __syncthreads();
    if (tid == 0) partials[bid] = sRed[0] + sRed[1] + sRed[2] + sRed[3];
}

__global__ void finalize_kernel(const float* __restrict__ partials, float* __restrict__ out) {
    const int tid = threadIdx.x;
    double s = 0.0;
    for (int i = tid; i < NBLK; i += 256) s += (double)partials[i];
    #pragma unroll
    for (int off = 32; off > 0; off >>= 1)
        s += __shfl_down(s, off, 64);
    __shared__ double sm[4];
    if ((tid & 63) == 0) sm[tid >> 6] = s;
    __syncthreads();
    if (tid == 0)
        out[0] = 1.0f - (float)((sm[0] + sm[1] + sm[2] + sm[3]) / (double)(4LL * 128 * 128 * 128));
}

extern "C" void kernel_launch(void* const* d_in, const int* in_sizes, int n_in,
                              void* d_out, int out_size, void* d_ws, size_t ws_size,
                              hipStream_t stream) {
    const float* img1 = (const float*)d_in[0];   // (4,2,128,128,128) fp32
    const float* img2 = (const float*)d_in[1];   // (4,1,128,128,128) fp32
    const float* win  = (const float*)d_in[2];   // (1,1,5,5,5) fp32
    float* out = (float*)d_out;
    float* ws  = (float*)d_ws;
    float* wfac     = ws;         // 16 floats
    float* partials = ws + 16;    // NBLK floats, fully rewritten every launch

    hipLaunchKernelGGL(factorize_window, dim3(1), dim3(64), 0, stream, win, wfac);
    hipLaunchKernelGGL(ssim_main, dim3(NBLK), dim3(256), 0, stream, img1, img2, wfac, partials);
    hipLaunchKernelGGL(finalize_kernel, dim3(1), dim3(256), 0, stream, partials, out);
}

// Round 8
// 184.874 us; speedup vs baseline: 4.7100x; 3.3924x over previous
//
#include <hip/hip_runtime.h>

// SSIM 3D, round 8. R3's exact proven structure (3 kernels, rolled 4x5-phase
// loop, DSUB=16, float2 ring[5][5], launch_bounds(256,4), VGPR 64 no-spill)
// with ONE change: W split into two 64-col tiles -> grid 2048 = 8 blocks/CU
// (R3's grid 1024 capped occupancy at 4 blocks/CU; barrier drains serialized).
// LDS per block drops to 10496 B. H/D phase: 128 active threads x 2 cols.
// Spill lore: 12 straight-line PHASE expansions spill (R4-R7); rolled 5-phase
// groups do not (R1-R3). Keep the rolled form. No wave_barrier intrinsics.

#define NDIM 128
#define TW64 64                // W tile
#define TH 4
#define WR (TH + 4)            // 8 W-conv rows
#define DSUB 16
#define NWT 2
#define NHT (NDIM / TH)        // 32
#define NDT (NDIM / DSUB)      // 8
#define NB 4
#define NBLK (NWT * NHT * NDT * NB)  // 2048

__global__ void factorize_window(const float* __restrict__ w, float* __restrict__ ws) {
    if (threadIdx.x == 0) {
        float w000 = w[0];
        #pragma unroll
        for (int i = 0; i < 5; ++i) ws[i]      = w[i * 25];
        #pragma unroll
        for (int j = 0; j < 5; ++j) ws[5 + j]  = w[j * 5] / w000;
        #pragma unroll
        for (int k = 0; k < 5; ++k) ws[10 + k] = w[k] / w000;
    }
}

__launch_bounds__(256, 4)
__global__ void ssim_main(const float* __restrict__ img1,
                          const float* __restrict__ img2,
                          const float* __restrict__ wfac,
                          float* __restrict__ partials) {
    const int bid = blockIdx.x;
    const int tw = bid % NWT;
    int t1 = bid / NWT;
    const int th = t1 % NHT; t1 /= NHT;
    const int td = t1 % NDT;
    const int b  = t1 / NDT;

    const int w0 = tw * TW64, h0 = th * TH, d0 = td * DSUB;
    const float* __restrict__ x1 = img1 + (size_t)(b * 2 + 1) * NDIM * NDIM * NDIM;
    const float* __restrict__ x2 = img2 + (size_t)b * NDIM * NDIM * NDIM;

    float uW[5], vW[5], tW[5];
    #pragma unroll
    for (int i = 0; i < 5; ++i) { uW[i] = wfac[i]; vW[i] = wfac[5 + i]; tW[i] = wfac[10 + i]; }

    __shared__ float sWc[5][WR][TW64];   // 10240 B
    __shared__ float sRed[4];

    const int tid  = threadIdx.x;
    // W-conv mapping: 8 rows x 32 col-groups of 2
    const int wrow = tid >> 5;           // 0..7
    const int wcg  = tid & 31;           // 0..31
    const int lc0  = wcg * 2;            // local col 0..62 (even)
    const int gc0  = w0 + lc0;           // global col (even)
    const int ghw  = h0 + wrow - 2;
    const bool haveL = (gc0 >= 2);
    const bool haveR = (gc0 <= 124);
    // H/D mapping: 128 active threads = 4 rows x 32 col-pairs of 2
    const bool active = (tid < 128);
    const int orow = tid >> 5;           // 0..3 for tid<128
    const int oc   = (tid & 31) * 2;     // local col, even

    float2 ring[5][5];                   // [slot][field], static indices only
    float2 accS = make_float2(0.f, 0.f);

#define PHASE(I, P) do {                                                       \
    const int i_ = (I);                                                        \
    const int d_ = d0 - 2 + i_;                                                \
    float2 A0 = make_float2(0,0), A1 = A0, A2 = A0;                            \
    float2 B0 = A0, B1 = A0, B2 = A0;                                          \
    if (((unsigned)d_ < NDIM) && ((unsigned)ghw < NDIM)) {                     \
        const float* __restrict__ r1_ = x1 + ((size_t)d_ * NDIM + ghw) * NDIM; \
        const float* __restrict__ r2_ = x2 + ((size_t)d_ * NDIM + ghw) * NDIM; \
        if (haveL) { A0 = *(const float2*)(r1_ + gc0 - 2);                     \
                     B0 = *(const float2*)(r2_ + gc0 - 2); }                   \
        A1 = *(const float2*)(r1_ + gc0);                                      \
        B1 = *(const float2*)(r2_ + gc0);                                      \
        if (haveR) { A2 = *(const float2*)(r1_ + gc0 + 2);                     \
                     B2 = *(const float2*)(r2_ + gc0 + 2); }                   \
    }                                                                          \
    float ra[6] = {A0.x, A0.y, A1.x, A1.y, A2.x, A2.y};                        \
    float rb[6] = {B0.x, B0.y, B1.x, B1.y, B2.x, B2.y};                        \
    float m1v[2], m2v[2], q11v[2], q22v[2], q12v[2];                           \
    _Pragma("unroll")                                                          \
    for (int k_ = 0; k_ < 2; ++k_) {                                           \
        float m1_=0.f, m2_=0.f, q11_=0.f, q22_=0.f, q12_=0.f;                  \
        _Pragma("unroll")                                                      \
        for (int c_ = 0; c_ < 5; ++c_) {                                       \
            const float a_ = ra[k_ + c_], b_ = rb[k_ + c_];                    \
            const float ta_ = tW[c_] * a_, tb_ = tW[c_] * b_;                  \
            m1_ += ta_; m2_ += tb_;                                            \
            q11_ += ta_ * a_; q22_ += tb_ * b_; q12_ += ta_ * b_;              \
        }                                                                      \
        m1v[k_]=m1_; m2v[k_]=m2_; q11v[k_]=q11_; q22v[k_]=q22_; q12v[k_]=q12_; \
    }                                                                          \
    __syncthreads();   /* prev phase's reads of sWc complete */                \
    *(float2*)&sWc[0][wrow][lc0] = make_float2(m1v[0], m1v[1]);                \
    *(float2*)&sWc[1][wrow][lc0] = make_float2(m2v[0], m2v[1]);                \
    *(float2*)&sWc[2][wrow][lc0] = make_float2(q11v[0], q11v[1]);              \
    *(float2*)&sWc[3][wrow][lc0] = make_float2(q22v[0], q22v[1]);              \
    *(float2*)&sWc[4][wrow][lc0] = make_float2(q12v[0], q12v[1]);              \
    __syncthreads();   /* writes visible */                                    \
    if (active) {                                                              \
        _Pragma("unroll")                                                      \
        for (int f_ = 0; f_ < 5; ++f_) {                                       \
            float2 F_ = make_float2(0.f, 0.f);                                 \
            _Pragma("unroll")                                                  \
            for (int r_ = 0; r_ < 5; ++r_) {                                   \
                const float2 wv_ = *(const float2*)&sWc[f_][orow + r_][oc];    \
                F_.x += vW[r_] * wv_.x;                                        \
                F_.y += vW[r_] * wv_.y;                                        \
            }                                                                  \
            ring[(P)][f_] = F_;                                                \
        }                                                                      \
        if (i_ >= 4) {                                                         \
            float2 F0 = make_float2(0,0), F1 = F0, F2 = F0, F3 = F0, F4 = F0;  \
            _Pragma("unroll")                                                  \
            for (int j_ = 0; j_ < 5; ++j_) {                                   \
                const int s_ = ((P) + 1 + j_) % 5;                             \
                const float uw_ = uW[j_];                                      \
                F0.x += uw_*ring[s_][0].x; F0.y += uw_*ring[s_][0].y;          \
                F1.x += uw_*ring[s_][1].x; F1.y += uw_*ring[s_][1].y;          \
                F2.x += uw_*ring[s_][2].x; F2.y += uw_*ring[s_][2].y;          \
                F3.x += uw_*ring[s_][3].x; F3.y += uw_*ring[s_][3].y;          \
                F4.x += uw_*ring[s_][4].x; F4.y += uw_*ring[s_][4].y;          \
            }                                                                  \
            {                                                                  \
                const float mu1 = F0.x, mu2 = F1.x;                            \
                const float m11 = mu1*mu1, m22 = mu2*mu2, m12 = mu1*mu2;       \
                const float num = (2.f*m12 + 1e-4f)*(2.f*(F4.x - m12) + 9e-4f);\
                const float den = (m11 + m22 + 1e-4f) *                        \
                                  ((F2.x - m11) + (F3.x - m22) + 9e-4f);       \
                accS.x += __fdividef(num, den);                                \
            }                                                                  \
            {                                                                  \
                const float mu1 = F0.y, mu2 = F1.y;                            \
                const float m11 = mu1*mu1, m22 = mu2*mu2, m12 = mu1*mu2;       \
                const float num = (2.f*m12 + 1e-4f)*(2.f*(F4.y - m12) + 9e-4f);\
                const float den = (m11 + m22 + 1e-4f) *                        \
                                  ((F2.y - m11) + (F3.y - m22) + 9e-4f);       \
                accS.y += __fdividef(num, den);                                \
            }                                                                  \
        }                                                                      \
    }                                                                          \
} while (0)

    // 20 slices: d0-2 .. d0+17, rolled 4 groups of 5 phases (R3-proven form)
    for (int io = 0; io < 4; ++io) {
        const int ib = io * 5;
        PHASE(ib + 0, 0);
        PHASE(ib + 1, 1);
        PHASE(ib + 2, 2);
        PHASE(ib + 3, 3);
        PHASE(ib + 4, 4);
    }
#undef PHASE

    float acc = accS.x + accS.y;
    #pragma unroll
    for (int off = 32; off > 0; off >>= 1)
        acc += __shfl_down(acc, off, 64);
    __syncthreads();
    if ((tid & 63) == 0) sRed[tid >> 6] = acc;
    __syncthreads();
    if (tid == 0) partials[bid] = sRed[0] + sRed[1] + sRed[2] + sRed[3];
}

__global__ void finalize_kernel(const float* __restrict__ partials, float* __restrict__ out) {
    const int tid = threadIdx.x;
    double s = 0.0;
    for (int i = tid; i < NBLK; i += 256) s += (double)partials[i];
    #pragma unroll
    for (int off = 32; off > 0; off >>= 1)
        s += __shfl_down(s, off, 64);
    __shared__ double sm[4];
    if ((tid & 63) == 0) sm[tid >> 6] = s;
    __syncthreads();
    if (tid == 0)
        out[0] = 1.0f - (float)((sm[0] + sm[1] + sm[2] + sm[3]) / (double)(4LL * 128 * 128 * 128));
}

extern "C" void kernel_launch(void* const* d_in, const int* in_sizes, int n_in,
                              void* d_out, int out_size, void* d_ws, size_t ws_size,
                              hipStream_t stream) {
    const float* img1 = (const float*)d_in[0];   // (4,2,128,128,128) fp32
    const float* img2 = (const float*)d_in[1];   // (4,1,128,128,128) fp32
    const float* win  = (const float*)d_in[2];   // (1,1,5,5,5) fp32
    float* out = (float*)d_out;
    float* ws  = (float*)d_ws;
    float* wfac     = ws;         // 16 floats
    float* partials = ws + 16;    // NBLK floats, fully rewritten every launch

    hipLaunchKernelGGL(factorize_window, dim3(1), dim3(64), 0, stream, win, wfac);
    hipLaunchKernelGGL(ssim_main, dim3(NBLK), dim3(256), 0, stream, img1, img2, wfac, partials);
    hipLaunchKernelGGL(finalize_kernel, dim3(1), dim3(256), 0, stream, partials, out);
}